// Round 7
// baseline (313.343 us; speedup 1.0000x reference)
//
#include <hip/hip_runtime.h>
#include <hip/hip_bf16.h>
#include <stdint.h>

#define D_MODEL 1024
#define NUM_EXPERTS 8
#define NBUCKET 16            // 8 primary + 8 secondary virtual experts
#define BM 128
#define BN 128
#define BK 64
#define GATE_TOK 16           // tokens per gate block (512 gate blocks)

typedef __bf16 bf16x8 __attribute__((ext_vector_type(8)));
typedef float f32x4 __attribute__((ext_vector_type(4)));

__device__ __forceinline__ unsigned short f32_to_bf16_rne(float f) {
    union { float f; uint32_t u; } v;
    v.f = f;
    uint32_t u = v.u;
    u += 0x7FFFu + ((u >> 16) & 1u);   // round-to-nearest-even
    return (unsigned short)(u >> 16);
}

__device__ __forceinline__ float bf16_to_f32(unsigned short h) {
    union { uint32_t u; float f; } v;
    v.u = ((uint32_t)h) << 16;
    return v.f;
}

// ---------------------------------------------------------------------------
// Fused prep kernel: blocks [0, nconv) convert We fp32->bf16; blocks
// [nconv, nconv+512) run the gate (Wg staged in LDS, fp64 logits ->
// strict-> top-2 with lower-index tie-break matching lax.top_k, softmax
// weights in fp32 (selection stays fp64-exact), 16-bucket block-aggregated
// append, fused x fp32->bf16 RNE conversion).
// ---------------------------------------------------------------------------
__global__ __launch_bounds__(256) void prep_kernel(
    const float* __restrict__ x, const float* __restrict__ Wg,
    const float* __restrict__ bg, const float* __restrict__ We,
    unsigned short* __restrict__ wbv, int T,
    int* __restrict__ counts, int* __restrict__ token_list,
    float* __restrict__ gate_list, unsigned short* __restrict__ xb,
    int nconv)
{
    const int tid = threadIdx.x;

    if ((int)blockIdx.x < nconv) {
        // ---- convert We: one float4 per thread ----
        int i = blockIdx.x * 256 + tid;
        float4 f = ((const float4*)We)[i];
        ushort4 o;
        o.x = f32_to_bf16_rne(f.x);
        o.y = f32_to_bf16_rne(f.y);
        o.z = f32_to_bf16_rne(f.z);
        o.w = f32_to_bf16_rne(f.w);
        ((ushort4*)wbv)[i] = o;
        return;
    }

    // ---- gate ----
    const int gb   = blockIdx.x - nconv;
    const int lane = tid & 63;
    const int wave = tid >> 6;
    const int tokBase = gb * GATE_TOK;

    __shared__ float4 WgS[NUM_EXPERTS * 256];   // 32 KB
    __shared__ double logitS[GATE_TOK][NUM_EXPERTS];
    __shared__ int cntS[NBUCKET];
    __shared__ int baseS[NBUCKET];

    if (tid < NBUCKET) cntS[tid] = 0;
#pragma unroll
    for (int i = 0; i < 8; i++)
        WgS[i * 256 + tid] = ((const float4*)Wg)[i * 256 + tid];
    __syncthreads();

    // Each wave handles 4 tokens; element k = q*256 + lane*4 + j.
    for (int tt = 0; tt < GATE_TOK / 4; tt++) {
        const int lt = wave * (GATE_TOK / 4) + tt;
        const int token = tokBase + lt;
        const float4* xr4 = (const float4*)(x + (size_t)token * D_MODEL);
        ushort4* xbr4 = (ushort4*)(xb + (size_t)token * D_MODEL);

        float4 xv[4];
#pragma unroll
        for (int q = 0; q < 4; q++) {
            float4 f = xr4[q * 64 + lane];
            xv[q] = f;
            ushort4 o;
            o.x = f32_to_bf16_rne(f.x);
            o.y = f32_to_bf16_rne(f.y);
            o.z = f32_to_bf16_rne(f.z);
            o.w = f32_to_bf16_rne(f.w);
            xbr4[q * 64 + lane] = o;
        }

        double acc[NUM_EXPERTS];
#pragma unroll
        for (int e = 0; e < NUM_EXPERTS; e++) {
            double a = 0.0;
#pragma unroll
            for (int q = 0; q < 4; q++) {
                float4 w = WgS[e * 256 + q * 64 + lane];
                a += (double)xv[q].x * (double)w.x;
                a += (double)xv[q].y * (double)w.y;
                a += (double)xv[q].z * (double)w.z;
                a += (double)xv[q].w * (double)w.w;
            }
            acc[e] = a;
        }
#pragma unroll
        for (int e = 0; e < NUM_EXPERTS; e++) {
            double a = acc[e];
            for (int off = 32; off > 0; off >>= 1) a += __shfl_xor(a, off, 64);
            acc[e] = a;
        }
        if (lane == 0) {
#pragma unroll
            for (int e = 0; e < NUM_EXPERTS; e++)
                logitS[lt][e] = acc[e] + (double)bg[e];
        }
    }
    __syncthreads();

    // Phase 2: one thread per token — top-2 + softmax + aggregated append.
    int i1 = 0, i2 = 0, o1 = 0, o2 = 0;
    float v1 = 0.f, v2 = 0.f;
    const int token2 = tokBase + tid;
    if (tid < GATE_TOK) {
        double lg[NUM_EXPERTS];
#pragma unroll
        for (int e = 0; e < NUM_EXPERTS; e++) lg[e] = logitS[tid][e];
        i1 = 0;
#pragma unroll
        for (int e = 1; e < NUM_EXPERTS; e++) if (lg[e] > lg[i1]) i1 = e;
        i2 = (i1 == 0) ? 1 : 0;
#pragma unroll
        for (int e = 0; e < NUM_EXPERTS; e++)
            if (e != i1 && lg[e] > lg[i2]) i2 = e;
        double m = lg[i1];
        float den = 0.f;
#pragma unroll
        for (int e = 0; e < NUM_EXPERTS; e++) den += __expf((float)(lg[e] - m));
        v1 = __expf((float)(lg[i1] - m)) / den;
        v2 = __expf((float)(lg[i2] - m)) / den;
        o1 = atomicAdd(&cntS[i1], 1);          // primary bucket e
        o2 = atomicAdd(&cntS[8 + i2], 1);      // secondary bucket 8+e
    }
    __syncthreads();
    if (tid < NBUCKET) baseS[tid] = atomicAdd(&counts[tid], cntS[tid]);
    __syncthreads();
    if (tid < GATE_TOK) {
        int p1 = i1 * T + baseS[i1] + o1;
        token_list[p1] = token2;
        gate_list[p1]  = v1;
        int p2 = (8 + i2) * T + baseS[8 + i2] + o2;
        token_list[p2] = token2;
        gate_list[p2]  = v2;
    }
}

// ---------------------------------------------------------------------------
// Per-bucket gathered GEMM, flatmm-style: NO LDS, NO barriers in the K-loop.
// Each wave loads its A/B MFMA fragments directly from global into VGPRs.
// Fragment row base pointers are fixed per lane (A row = gathered token row,
// B row = weight row; +qq*16 bakes the quad k-offset); the fully-unrolled
// K-loop makes every load "base + constant offset" (max 1984 < 4KB imm) —
// zero address math in the loop. Manual depth-2 tile pipeline: tile k+1's
// 16 fragment loads are in flight while tile k's 32 MFMAs run, so the
// compiler emits fine-grained vmcnt(N>0) waits (the hipBLASLt pattern the
// 2-barrier LDS shape cannot express — R3/R6 both plateaued on the
// vmcnt(0)-before-s_barrier drain). Per instruction a wave reads 16 rows x
// 64B aligned chunks = full cache lines; rows are L2-resident (16-32x reuse).
// Epilogue: plain bf16 stores to ybuf[slot][token][:], no atomics.
// ---------------------------------------------------------------------------
__global__ __launch_bounds__(256) void moe_gemm(
    const unsigned short* __restrict__ xb,   // [T][1024] bf16
    const unsigned short* __restrict__ wb,   // [E][1024][1024] bf16, K-contig
    const float* __restrict__ be,            // [E][1024]
    const int* __restrict__ counts,          // [16]
    const int* __restrict__ token_list,      // [16][T]
    const float* __restrict__ gate_list,     // [16][T]
    unsigned short* __restrict__ ybuf,       // [2][T][1024] bf16
    int T)
{
    const int bid = blockIdx.x;
    const int nt = bid & 7;
    const int rest = bid >> 3;
    const int vexp = rest & 15;
    const int mt = rest >> 4;
    const int e_w = vexp & 7;

    const int n_e = counts[vexp];
    const int m0 = mt * BM;
    if (m0 >= n_e) return;
    const int n0 = nt * BN;
    const int tid = threadIdx.x;
    const int wave = tid >> 6, lane = tid & 63;
    const int wm = (wave >> 1) * 64, wn = (wave & 1) * 64;
    const int frow = lane & 15;
    const int qq = lane >> 4;

    const int* tl = token_list + vexp * T;
    const float* gl = gate_list + vexp * T;

    // Per-lane fragment row base pointers. A[mi]: gathered token row for
    // m = m0+wm+mi*16+frow (clamped to token 0 if past n_e — computed but
    // never stored). B[ni]: weight row n = n0+wn+ni*16+frow of expert e_w.
    const char* ap[4];
    const char* bp[4];
    {
        const char* xc = (const char*)xb;
        const char* wc = (const char*)(wb + (size_t)e_w * D_MODEL * D_MODEL);
#pragma unroll
        for (int i = 0; i < 4; i++) {
            int gr = m0 + wm + i * 16 + frow;
            int tk = (gr < n_e) ? tl[gr] : 0;
            ap[i] = xc + (size_t)tk * (D_MODEL * 2) + qq * 16;
            bp[i] = wc + (size_t)(n0 + wn + i * 16 + frow) * (D_MODEL * 2) + qq * 16;
        }
    }

    // Preload this thread's 4 bias values (constant across mi,r).
    float bev[4];
#pragma unroll
    for (int ni = 0; ni < 4; ni++)
        bev[ni] = be[e_w * D_MODEL + n0 + wn + ni * 16 + frow];

    f32x4 acc[4][4];
#pragma unroll
    for (int mi = 0; mi < 4; mi++)
#pragma unroll
        for (int ni = 0; ni < 4; ni++)
            acc[mi][ni] = (f32x4){0.f, 0.f, 0.f, 0.f};

    // Double-buffered fragment registers: [mi][ks] and [ni][ks].
    bf16x8 a0[4][2], b0[4][2], a1[4][2], b1[4][2];

#define LOADT(A, B, KB)                                              \
    {                                                                \
        _Pragma("unroll") for (int mi = 0; mi < 4; mi++) {           \
            A[mi][0] = *(const bf16x8*)(ap[mi] + (KB));              \
            A[mi][1] = *(const bf16x8*)(ap[mi] + (KB) + 64);         \
            B[mi][0] = *(const bf16x8*)(bp[mi] + (KB));              \
            B[mi][1] = *(const bf16x8*)(bp[mi] + (KB) + 64);         \
        }                                                            \
    }

#define MFMAT(A, B)                                                  \
    {                                                                \
        _Pragma("unroll") for (int ks = 0; ks < 2; ks++)             \
        _Pragma("unroll") for (int mi = 0; mi < 4; mi++)             \
        _Pragma("unroll") for (int ni = 0; ni < 4; ni++)             \
            acc[mi][ni] = __builtin_amdgcn_mfma_f32_16x16x32_bf16(   \
                A[mi][ks], B[ni][ks], acc[mi][ni], 0, 0, 0);         \
    }

    LOADT(a0, b0, 0);
#pragma unroll
    for (int kt2 = 0; kt2 < 8; kt2++) {
        const int base = kt2 * 256;                 // bytes (constant: full unroll)
        LOADT(a1, b1, base + 128);                  // tile 2*kt2+1 in flight
        MFMAT(a0, b0);                              // compute tile 2*kt2
        if (kt2 < 7) LOADT(a0, b0, base + 256);     // tile 2*kt2+2 in flight
        MFMAT(a1, b1);                              // compute tile 2*kt2+1
    }
#undef LOADT
#undef MFMAT

    // Epilogue: C/D layout col = lane&15 (=frow), row = qq*4 + r.
    unsigned short* ybase = ybuf + (size_t)(vexp >> 3) * T * D_MODEL;
    const int rbase = qq * 4;
#pragma unroll
    for (int mi = 0; mi < 4; mi++) {
#pragma unroll
        for (int r = 0; r < 4; r++) {
            int lrow = wm + mi * 16 + rbase + r;
            int gr = m0 + lrow;
            if (gr < n_e) {
                int   tk = tl[gr];
                float gv = gl[gr];
                unsigned short* yr = ybase + (size_t)tk * D_MODEL;
#pragma unroll
                for (int ni = 0; ni < 4; ni++) {
                    int c = n0 + wn + ni * 16 + frow;
                    yr[c] = f32_to_bf16_rne(gv * (acc[mi][ni][r] + bev[ni]));
                }
            }
        }
    }
}

// ---------------------------------------------------------------------------
// Combine: out[t][d] = ybuf[0][t][d] + ybuf[1][t][d]  (bf16 -> fp32 add)
// ---------------------------------------------------------------------------
__global__ __launch_bounds__(256) void combine_kernel(
    const unsigned short* __restrict__ y0,
    const unsigned short* __restrict__ y1,
    float* __restrict__ out, int n4)
{
    int i = blockIdx.x * 256 + threadIdx.x;
    if (i >= n4) return;
    ushort4 a = ((const ushort4*)y0)[i];
    ushort4 b = ((const ushort4*)y1)[i];
    float4 o;
    o.x = bf16_to_f32(a.x) + bf16_to_f32(b.x);
    o.y = bf16_to_f32(a.y) + bf16_to_f32(b.y);
    o.z = bf16_to_f32(a.z) + bf16_to_f32(b.z);
    o.w = bf16_to_f32(a.w) + bf16_to_f32(b.w);
    ((float4*)out)[i] = o;
}

extern "C" void kernel_launch(void* const* d_in, const int* in_sizes, int n_in,
                              void* d_out, int out_size, void* d_ws, size_t ws_size,
                              hipStream_t stream) {
    const float* x  = (const float*)d_in[0];
    const float* Wg = (const float*)d_in[1];
    const float* bg = (const float*)d_in[2];
    const float* We = (const float*)d_in[3];
    const float* be = (const float*)d_in[4];
    // top_k (d_in[5]) is fixed at 2 per the reference; hard-coded.

    const int T = in_sizes[0] / D_MODEL;   // 8192 tokens

    // workspace carve-up (~103 MB total)
    char* ws = (char*)d_ws;
    unsigned short* xb = (unsigned short*)ws;                       // T*D bf16
    size_t off = (size_t)T * D_MODEL * 2;
    unsigned short* wbv = (unsigned short*)(ws + off);              // E*D*D bf16
    off += (size_t)NUM_EXPERTS * D_MODEL * D_MODEL * 2;
    int* counts = (int*)(ws + off);         off += 256;
    int* token_list = (int*)(ws + off);     off += (size_t)NBUCKET * T * 4;
    float* gate_list = (float*)(ws + off);  off += (size_t)NBUCKET * T * 4;
    unsigned short* ybuf = (unsigned short*)(ws + off);             // 2*T*D bf16
    off += (size_t)2 * T * D_MODEL * 2;

    hipMemsetAsync(counts, 0, 256, stream);

    const int nconv = NUM_EXPERTS * D_MODEL * D_MODEL / 4 / 256;   // 8192
    const int ngate = T / GATE_TOK;                                // 512
    prep_kernel<<<nconv + ngate, 256, 0, stream>>>(
        x, Wg, bg, We, wbv, T, counts, token_list, gate_list, xb, nconv);

    // grid: nt (8) fastest x vexp (16) x mt (64, worst case)
    moe_gemm<<<8 * 16 * 64, 256, 0, stream>>>(
        xb, wbv, be, counts, token_list, gate_list, ybuf, T);

    int n4c = T * D_MODEL / 4;
    combine_kernel<<<(n4c + 255) / 256, 256, 0, stream>>>(
        ybuf, ybuf + (size_t)T * D_MODEL, (float*)d_out, n4c);
}

// Round 8
// 231.358 us; speedup vs baseline: 1.3544x; 1.3544x over previous
//
#include <hip/hip_runtime.h>
#include <hip/hip_bf16.h>
#include <stdint.h>

#define D_MODEL 1024
#define NUM_EXPERTS 8
#define NBUCKET 16            // 8 primary + 8 secondary virtual experts
#define BM 128
#define BN 128
#define BK 64
#define GATE_TOK 16           // tokens per gate block (512 gate blocks)

typedef __bf16 bf16x8 __attribute__((ext_vector_type(8)));
typedef float f32x4 __attribute__((ext_vector_type(4)));

__device__ __forceinline__ unsigned short f32_to_bf16_rne(float f) {
    union { float f; uint32_t u; } v;
    v.f = f;
    uint32_t u = v.u;
    u += 0x7FFFu + ((u >> 16) & 1u);   // round-to-nearest-even
    return (unsigned short)(u >> 16);
}

__device__ __forceinline__ float bf16_to_f32(unsigned short h) {
    union { uint32_t u; float f; } v;
    v.u = ((uint32_t)h) << 16;
    return v.f;
}

__device__ __forceinline__ void gload_lds16(const unsigned short* g, unsigned short* l) {
    __builtin_amdgcn_global_load_lds(
        (const __attribute__((address_space(1))) void*)g,
        (__attribute__((address_space(3))) void*)l,
        16, 0, 0);
}

// ---------------------------------------------------------------------------
// Fused prep kernel: blocks [0, nconv) convert We fp32->bf16; blocks
// [nconv, nconv+512) run the gate (Wg staged in LDS, fp64 logits ->
// strict-> top-2 with lower-index tie-break matching lax.top_k, softmax
// weights in fp32 (selection stays fp64-exact), 16-bucket block-aggregated
// append, fused x fp32->bf16 RNE conversion).
// ---------------------------------------------------------------------------
__global__ __launch_bounds__(256) void prep_kernel(
    const float* __restrict__ x, const float* __restrict__ Wg,
    const float* __restrict__ bg, const float* __restrict__ We,
    unsigned short* __restrict__ wbv, int T,
    int* __restrict__ counts, int* __restrict__ token_list,
    float* __restrict__ gate_list, unsigned short* __restrict__ xb,
    int nconv)
{
    const int tid = threadIdx.x;

    if ((int)blockIdx.x < nconv) {
        // ---- convert We: one float4 per thread ----
        int i = blockIdx.x * 256 + tid;
        float4 f = ((const float4*)We)[i];
        ushort4 o;
        o.x = f32_to_bf16_rne(f.x);
        o.y = f32_to_bf16_rne(f.y);
        o.z = f32_to_bf16_rne(f.z);
        o.w = f32_to_bf16_rne(f.w);
        ((ushort4*)wbv)[i] = o;
        return;
    }

    // ---- gate ----
    const int gb   = blockIdx.x - nconv;
    const int lane = tid & 63;
    const int wave = tid >> 6;
    const int tokBase = gb * GATE_TOK;

    __shared__ float4 WgS[NUM_EXPERTS * 256];   // 32 KB
    __shared__ double logitS[GATE_TOK][NUM_EXPERTS];
    __shared__ int cntS[NBUCKET];
    __shared__ int baseS[NBUCKET];

    if (tid < NBUCKET) cntS[tid] = 0;
#pragma unroll
    for (int i = 0; i < 8; i++)
        WgS[i * 256 + tid] = ((const float4*)Wg)[i * 256 + tid];
    __syncthreads();

    // Each wave handles 4 tokens; element k = q*256 + lane*4 + j.
    for (int tt = 0; tt < GATE_TOK / 4; tt++) {
        const int lt = wave * (GATE_TOK / 4) + tt;
        const int token = tokBase + lt;
        const float4* xr4 = (const float4*)(x + (size_t)token * D_MODEL);
        ushort4* xbr4 = (ushort4*)(xb + (size_t)token * D_MODEL);

        float4 xv[4];
#pragma unroll
        for (int q = 0; q < 4; q++) {
            float4 f = xr4[q * 64 + lane];
            xv[q] = f;
            ushort4 o;
            o.x = f32_to_bf16_rne(f.x);
            o.y = f32_to_bf16_rne(f.y);
            o.z = f32_to_bf16_rne(f.z);
            o.w = f32_to_bf16_rne(f.w);
            xbr4[q * 64 + lane] = o;
        }

        double acc[NUM_EXPERTS];
#pragma unroll
        for (int e = 0; e < NUM_EXPERTS; e++) {
            double a = 0.0;
#pragma unroll
            for (int q = 0; q < 4; q++) {
                float4 w = WgS[e * 256 + q * 64 + lane];
                a += (double)xv[q].x * (double)w.x;
                a += (double)xv[q].y * (double)w.y;
                a += (double)xv[q].z * (double)w.z;
                a += (double)xv[q].w * (double)w.w;
            }
            acc[e] = a;
        }
#pragma unroll
        for (int e = 0; e < NUM_EXPERTS; e++) {
            double a = acc[e];
            for (int off = 32; off > 0; off >>= 1) a += __shfl_xor(a, off, 64);
            acc[e] = a;
        }
        if (lane == 0) {
#pragma unroll
            for (int e = 0; e < NUM_EXPERTS; e++)
                logitS[lt][e] = acc[e] + (double)bg[e];
        }
    }
    __syncthreads();

    // Phase 2: one thread per token — top-2 + softmax + aggregated append.
    int i1 = 0, i2 = 0, o1 = 0, o2 = 0;
    float v1 = 0.f, v2 = 0.f;
    const int token2 = tokBase + tid;
    if (tid < GATE_TOK) {
        double lg[NUM_EXPERTS];
#pragma unroll
        for (int e = 0; e < NUM_EXPERTS; e++) lg[e] = logitS[tid][e];
        i1 = 0;
#pragma unroll
        for (int e = 1; e < NUM_EXPERTS; e++) if (lg[e] > lg[i1]) i1 = e;
        i2 = (i1 == 0) ? 1 : 0;
#pragma unroll
        for (int e = 0; e < NUM_EXPERTS; e++)
            if (e != i1 && lg[e] > lg[i2]) i2 = e;
        double m = lg[i1];
        float den = 0.f;
#pragma unroll
        for (int e = 0; e < NUM_EXPERTS; e++) den += __expf((float)(lg[e] - m));
        v1 = __expf((float)(lg[i1] - m)) / den;
        v2 = __expf((float)(lg[i2] - m)) / den;
        o1 = atomicAdd(&cntS[i1], 1);          // primary bucket e
        o2 = atomicAdd(&cntS[8 + i2], 1);      // secondary bucket 8+e
    }
    __syncthreads();
    if (tid < NBUCKET) baseS[tid] = atomicAdd(&counts[tid], cntS[tid]);
    __syncthreads();
    if (tid < GATE_TOK) {
        int p1 = i1 * T + baseS[i1] + o1;
        token_list[p1] = token2;
        gate_list[p1]  = v1;
        int p2 = (8 + i2) * T + baseS[8 + i2] + o2;
        token_list[p2] = token2;
        gate_list[p2]  = v2;
    }
}

// ---------------------------------------------------------------------------
// Per-bucket gathered GEMM — R3's proven structure (74.5 us measured):
// single-buffered global_load_lds(16B) staging, 2-barrier K-loop, nt-fastest
// bid map (R4's XCD pinning regressed; R5/R7 register pipelines spilled or
// were de-pipelined by the allocator; R6 LDS dbuf neutral). One change vs
// R3: LDS is EXACTLY 32768 B (tokS/gateS dropped; token/gate lookups read
// global directly — tiny, L2-hot, 16-lane broadcast) in case the allocator
// rounds 33792 up a granule and costs a resident block/CU.
// XOR-swizzled LDS (16B chunks): zero bank conflicts (measured R3).
// Epilogue: plain bf16 stores to ybuf[slot][token][:], no atomics.
// ---------------------------------------------------------------------------
__global__ __launch_bounds__(256) void moe_gemm(
    const unsigned short* __restrict__ xb,   // [T][1024] bf16
    const unsigned short* __restrict__ wb,   // [E][1024][1024] bf16, K-contig
    const float* __restrict__ be,            // [E][1024]
    const int* __restrict__ counts,          // [16]
    const int* __restrict__ token_list,      // [16][T]
    const float* __restrict__ gate_list,     // [16][T]
    unsigned short* __restrict__ ybuf,       // [2][T][1024] bf16
    int T)
{
    const int bid = blockIdx.x;
    const int nt = bid & 7;
    const int rest = bid >> 3;
    const int vexp = rest & 15;
    const int mt = rest >> 4;
    const int e_w = vexp & 7;

    const int n_e = counts[vexp];
    const int m0 = mt * BM;
    if (m0 >= n_e) return;
    const int n0 = nt * BN;
    const int tid = threadIdx.x;

    __shared__ __align__(16) unsigned short As[BM * BK];
    __shared__ __align__(16) unsigned short Bs[BN * BK];

    // Staging sources, with XOR swizzle on the 16B segment index.
    const unsigned short* asrc[4];
    const unsigned short* bsrc[4];
    const unsigned short* wbase = wb + (size_t)e_w * D_MODEL * D_MODEL;
    const int* tl = token_list + vexp * T;
    const float* gl = gate_list + vexp * T;
#pragma unroll
    for (int i = 0; i < 4; i++) {
        int flat = i * 256 + tid;
        int r = flat >> 3, seg = flat & 7;
        int ss = seg ^ (r & 7);
        int gr = m0 + r;
        int tk = (gr < n_e) ? tl[gr] : 0;
        asrc[i] = xb + (size_t)tk * D_MODEL + ss * 8;
        bsrc[i] = wbase + (size_t)(n0 + r) * D_MODEL + ss * 8;
    }

    const int wave = tid >> 6, lane = tid & 63;
    const int wm = (wave >> 1) * 64, wn = (wave & 1) * 64;
    const int frow = lane & 15;
    const int qq = lane >> 4;
    const int sw8 = frow & 7;
    const int col = lane & 15;

    // Preload this thread's 4 bias values (constant across mi,r).
    float bev[4];
#pragma unroll
    for (int ni = 0; ni < 4; ni++)
        bev[ni] = be[e_w * D_MODEL + n0 + wn + ni * 16 + col];

    f32x4 acc[4][4];
#pragma unroll
    for (int mi = 0; mi < 4; mi++)
#pragma unroll
        for (int ni = 0; ni < 4; ni++)
            acc[mi][ni] = (f32x4){0.f, 0.f, 0.f, 0.f};

    for (int kt = 0; kt < D_MODEL / BK; kt++) {
        const int k0 = kt * BK;
#pragma unroll
        for (int i = 0; i < 4; i++) {
            int flat = i * 256 + tid;
            gload_lds16(asrc[i] + k0, &As[flat * 8]);
            gload_lds16(bsrc[i] + k0, &Bs[flat * 8]);
        }
        __syncthreads();
#pragma unroll
        for (int ks = 0; ks < 2; ks++) {
            const int off = ((ks * 4 + qq) ^ sw8) * 8;   // swizzled k-offset (halfs)
            bf16x8 af[4], bfv[4];
#pragma unroll
            for (int mi = 0; mi < 4; mi++)
                af[mi] = *(const bf16x8*)&As[(wm + mi * 16 + frow) * BK + off];
#pragma unroll
            for (int ni = 0; ni < 4; ni++)
                bfv[ni] = *(const bf16x8*)&Bs[(wn + ni * 16 + frow) * BK + off];
#pragma unroll
            for (int mi = 0; mi < 4; mi++)
#pragma unroll
                for (int ni = 0; ni < 4; ni++)
                    acc[mi][ni] = __builtin_amdgcn_mfma_f32_16x16x32_bf16(
                        af[mi], bfv[ni], acc[mi][ni], 0, 0, 0);
        }
        __syncthreads();
    }

    // Epilogue: C/D layout col = lane&15, row = (lane>>4)*4 + reg.
    unsigned short* ybase = ybuf + (size_t)(vexp >> 3) * T * D_MODEL;
    const int rbase = (lane >> 4) * 4;
#pragma unroll
    for (int mi = 0; mi < 4; mi++) {
#pragma unroll
        for (int r = 0; r < 4; r++) {
            int lrow = wm + mi * 16 + rbase + r;
            int gr = m0 + lrow;
            if (gr < n_e) {
                int   tk = tl[gr];
                float gv = gl[gr];
                unsigned short* yr = ybase + (size_t)tk * D_MODEL;
#pragma unroll
                for (int ni = 0; ni < 4; ni++) {
                    int c = n0 + wn + ni * 16 + col;
                    yr[c] = f32_to_bf16_rne(gv * (acc[mi][ni][r] + bev[ni]));
                }
            }
        }
    }
}

// ---------------------------------------------------------------------------
// Combine: out[t][d] = ybuf[0][t][d] + ybuf[1][t][d]  (bf16 -> fp32 add)
// ---------------------------------------------------------------------------
__global__ __launch_bounds__(256) void combine_kernel(
    const unsigned short* __restrict__ y0,
    const unsigned short* __restrict__ y1,
    float* __restrict__ out, int n4)
{
    int i = blockIdx.x * 256 + threadIdx.x;
    if (i >= n4) return;
    ushort4 a = ((const ushort4*)y0)[i];
    ushort4 b = ((const ushort4*)y1)[i];
    float4 o;
    o.x = bf16_to_f32(a.x) + bf16_to_f32(b.x);
    o.y = bf16_to_f32(a.y) + bf16_to_f32(b.y);
    o.z = bf16_to_f32(a.z) + bf16_to_f32(b.z);
    o.w = bf16_to_f32(a.w) + bf16_to_f32(b.w);
    ((float4*)out)[i] = o;
}

extern "C" void kernel_launch(void* const* d_in, const int* in_sizes, int n_in,
                              void* d_out, int out_size, void* d_ws, size_t ws_size,
                              hipStream_t stream) {
    const float* x  = (const float*)d_in[0];
    const float* Wg = (const float*)d_in[1];
    const float* bg = (const float*)d_in[2];
    const float* We = (const float*)d_in[3];
    const float* be = (const float*)d_in[4];
    // top_k (d_in[5]) is fixed at 2 per the reference; hard-coded.

    const int T = in_sizes[0] / D_MODEL;   // 8192 tokens

    // workspace carve-up (~103 MB total)
    char* ws = (char*)d_ws;
    unsigned short* xb = (unsigned short*)ws;                       // T*D bf16
    size_t off = (size_t)T * D_MODEL * 2;
    unsigned short* wbv = (unsigned short*)(ws + off);              // E*D*D bf16
    off += (size_t)NUM_EXPERTS * D_MODEL * D_MODEL * 2;
    int* counts = (int*)(ws + off);         off += 256;
    int* token_list = (int*)(ws + off);     off += (size_t)NBUCKET * T * 4;
    float* gate_list = (float*)(ws + off);  off += (size_t)NBUCKET * T * 4;
    unsigned short* ybuf = (unsigned short*)(ws + off);             // 2*T*D bf16
    off += (size_t)2 * T * D_MODEL * 2;

    hipMemsetAsync(counts, 0, 256, stream);

    const int nconv = NUM_EXPERTS * D_MODEL * D_MODEL / 4 / 256;   // 8192
    const int ngate = T / GATE_TOK;                                // 512
    prep_kernel<<<nconv + ngate, 256, 0, stream>>>(
        x, Wg, bg, We, wbv, T, counts, token_list, gate_list, xb, nconv);

    // grid: nt (8) fastest x vexp (16) x mt (64, worst case)
    moe_gemm<<<8 * 16 * 64, 256, 0, stream>>>(
        xb, wbv, be, counts, token_list, gate_list, ybuf, T);

    int n4c = T * D_MODEL / 4;
    combine_kernel<<<(n4c + 255) / 256, 256, 0, stream>>>(
        ybuf, ybuf + (size_t)T * D_MODEL, (float*)d_out, n4c);
}